// Round 4
// baseline (3663.434 us; speedup 1.0000x reference)
//
#include <hip/hip_runtime.h>
#include <math.h>

#define N 64
#define MAX_ITER 5

__device__ __forceinline__ float rl(float x, int lane) {
    return __uint_as_float(__builtin_amdgcn_readlane(__float_as_uint(x), lane));
}

// 128 threads = 2 waves per 64x64 SPD matrix (producer/consumer split).
//   wave 0 (QR): a[] = A columns; Householder phase 1 (no qt work), archive
//     V/R to G (swizzled rows, diag := v0) + betas to P; then r-pass
//     (A_next = R*Q rows) in place on a[] — bit-identical to the prior
//     single-wave kernel's A/R/diag trajectory.
//   wave 1 (Q):  a[] = Qt rows; per iteration applies H0..H62 using the SAME
//     G-broadcast k-loop (v_k rows from G, beta from P via readlane).
// Rationale: the single-wave version kept qt[] cold across the phase-2 loop;
// LLVM's RA spills cold 64-float ranges around loops regardless of VGPR
// budget (measured: 328 MB scratch writes = exactly one array/iter). With the
// split, each wave's peak live set is ONE array (~85-100 regs) -> no spill,
// and LDS (16.6 KB) allows 9 blocks/CU = 18 waves/CU for latency hiding.
__global__ __launch_bounds__(128)
void logm_kernel(const float* __restrict__ gin, float* __restrict__ gout) {
    __shared__ __align__(16) float G[N * N];  // V/R archive; U rows in epilogue
    __shared__ float P[N];                    // beta_k broadcast; sm[] in epilogue
    const int t = threadIdx.x & 63;
    const bool isQR = threadIdx.x < 64;       // wave 0
    const long b = blockIdx.x;
    const float* __restrict__ in = gin + b * (long)(N * N);
    float* __restrict__ out = gout + b * (long)(N * N);

    float a[N];   // wave0: A columns / A_next rows; wave1: Qt rows
    if (isQR) {
        #pragma unroll
        for (int i = 0; i < N; ++i) a[i] = in[i * N + t];
    } else {
        #pragma unroll
        for (int i = 0; i < N; ++i) a[i] = (i == t) ? 1.0f : 0.0f;
    }

    float betaS = 0.f, v0S = 0.f, alS = 0.f, diagR = 0.f;

    for (int iter = 0; iter < MAX_ITER; ++iter) {
        if (isQR) {
            // ============ Phase 1: Householder QR on a[] (columns only) ============
            float dotA, wA;
            {   // prologue: deferred dot for k=0 (raw coefficient x0 at i=0)
                float dA0 = 0.f, dA1 = 0.f;
                #pragma unroll
                for (int i = 0; i < N; ++i) {
                    const float c = rl(a[i], 0);
                    if (i & 1) dA1 = fmaf(c, a[i], dA1);
                    else       dA0 = fmaf(c, a[i], dA0);
                }
                dotA = dA0 + dA1; wA = a[0];
            }
            #pragma unroll
            for (int kb = 0; kb < 8; ++kb) {
                const int dkEnd = (kb == 7) ? 7 : 8;      // k stops at 62
                for (int dk = 0; dk < dkEnd; ++dk) {
                    const int k = 8 * kb + dk;
                    const int k1 = k + 1;
                    const float ss = rl(dotA, k);         // tail norm ||A[k:,k]||^2
                    const float x0 = rl(wA, k);           // A[k][k]
                    const float nrm = sqrtf(ss);
                    const float alpha = (x0 >= 0.f) ? -nrm : nrm;
                    const float v0 = x0 - alpha;
                    const float vtv = fmaf(v0, v0, ss - x0 * x0);
                    const float beta = (vtv > 1e-30f) ? __fdividef(2.0f, vtv) : 0.f;
                    const float ca = beta * fmaf(-alpha, wA, dotA);  // deferred-coef fix
                    const float caE = (t > k) ? ca : 0.f; // freeze columns <= k
                    betaS = (t == k) ? beta  : betaS;
                    v0S   = (t == k) ? v0    : v0S;
                    alS   = (t == k) ? alpha : alS;

                    float nA0 = 0.f, nA1 = 0.f, nwA = 0.f;
                    #pragma unroll
                    for (int i0 = 8 * kb; i0 < N; i0 += 8) {
                        #pragma unroll
                        for (int u = 0; u < 8; ++u) {
                            const int i = i0 + u;
                            float cu = rl(a[i], k);       // v_k[i] from lane k
                            if (i0 == 8 * kb) cu = (i > k) ? cu : ((i == k) ? v0 : 0.f);
                            a[i] = fmaf(-caE, cu, a[i]);
                            float c2 = rl(a[i], k1);      // post-update col k+1 (raw)
                            if (i0 == 8 * kb) c2 = (i > k) ? c2 : 0.f;
                            if (u & 1) nA1 = fmaf(c2, a[i], nA1);
                            else       nA0 = fmaf(c2, a[i], nA0);
                            if ((i0 == 8 * kb && u > 0) || (kb < 7 && i0 == 8 * kb + 8 && u == 0)) {
                                nwA = (i == k1) ? a[i] : nwA;
                            }
                        }
                    }
                    dotA = nA0 + nA1; wA = nwA;
                }
            }
            // ==== Archive columns -> G rows (swizzled); diag := v0; publish betas ====
            diagR = (t == N - 1) ? a[N - 1] : alS;        // R's diagonal (kept in reg)
            #pragma unroll
            for (int j = 0; j < N; j += 4) {
                float4 w; w.x = a[j]; w.y = a[j + 1]; w.z = a[j + 2]; w.w = a[j + 3];
                *reinterpret_cast<float4*>(&G[(t << 6) + ((j + (t << 2)) & 63)]) = w;
            }
            G[(t << 6) + ((5 * t) & 63)] = v0S;           // diag of row t = v0_t
            P[t] = betaS;
        }
        __syncthreads();                                   // G, P ready for both waves

        // ====== Shared H-application pass: wave0 -> r rows, wave1 -> Qt rows ======
        {
            const float bq = P[t];                         // lane k holds beta_k
            if (isQR) {                                    // init r = row t of R
                #pragma unroll
                for (int j = 0; j < N; ++j) {
                    const float g = G[(j << 6) + ((t + (j << 2)) & 63)];
                    a[j] = (j > t) ? g : ((j == t) ? diagR : 0.f);
                }
            }                                              // wave1: a[] = Qt rows already
            float dd;                                      // running dot v_k . row
            {
                float d0 = 0.f, d1 = 0.f;
                #pragma unroll
                for (int j = 0; j < N; j += 4) {           // row 0 of G = exact v_0
                    const float4 v = *reinterpret_cast<const float4*>(&G[j]);
                    d0 = fmaf(v.x, a[j],     d0);
                    d1 = fmaf(v.y, a[j + 1], d1);
                    d0 = fmaf(v.z, a[j + 2], d0);
                    d1 = fmaf(v.w, a[j + 3], d1);
                }
                dd = d0 + d1;
            }
            for (int k = 0; k < N - 1; ++k) {
                const int k1 = k + 1;
                const float cc = rl(bq, k) * dd;
                float nD0 = 0.f, nD1 = 0.f;
                #pragma unroll
                for (int j0 = 0; j0 < N; j0 += 8) {
                    if (j0 + 8 > k) {                      // uniform skip of dead blocks
                        #pragma unroll
                        for (int h = 0; h < 2; ++h) {
                            const int jc = j0 + 4 * h;
                            float4 vk  = *reinterpret_cast<const float4*>(
                                &G[(k  << 6) + ((jc + (k  << 2)) & 63)]);
                            float4 vk1 = *reinterpret_cast<const float4*>(
                                &G[(k1 << 6) + ((jc + (k1 << 2)) & 63)]);
                            if (jc <= k) {                 // only the block containing k
                                vk.x  = (jc + 0 >= k)  ? vk.x  : 0.f;  // j==k keeps v0
                                vk.y  = (jc + 1 >= k)  ? vk.y  : 0.f;
                                vk.z  = (jc + 2 >= k)  ? vk.z  : 0.f;
                                vk.w  = (jc + 3 >= k)  ? vk.w  : 0.f;
                                vk1.x = (jc + 0 >= k1) ? vk1.x : 0.f;
                                vk1.y = (jc + 1 >= k1) ? vk1.y : 0.f;
                                vk1.z = (jc + 2 >= k1) ? vk1.z : 0.f;
                                vk1.w = (jc + 3 >= k1) ? vk1.w : 0.f;
                            }
                            a[jc + 0] = fmaf(-cc, vk.x, a[jc + 0]); nD0 = fmaf(vk1.x, a[jc + 0], nD0);
                            a[jc + 1] = fmaf(-cc, vk.y, a[jc + 1]); nD1 = fmaf(vk1.y, a[jc + 1], nD1);
                            a[jc + 2] = fmaf(-cc, vk.z, a[jc + 2]); nD0 = fmaf(vk1.z, a[jc + 2], nD0);
                            a[jc + 3] = fmaf(-cc, vk.w, a[jc + 3]); nD1 = fmaf(vk1.w, a[jc + 3], nD1);
                        }
                    }
                }
                dd = nD0 + nD1;
            }
        }
        __syncthreads();   // both passes done before next archive overwrites G/P
        // wave0: a[] = rows of A_next = columns of next A (symmetry). wave1: a[] = Qt.
    }

    // ======= Epilogue: sm = log(clip(diag A5)); X = U diag(sm) U^T =======
    if (isQR) {
        P[t] = __logf(fmaxf(a[t], 1e-6f));                // a[t] on lane t = A5[t][t]
    } else {
        #pragma unroll
        for (int l = 0; l < N; l += 4) {                  // U rows -> G (swizzled)
            float4 w; w.x = a[l]; w.y = a[l + 1]; w.z = a[l + 2]; w.w = a[l + 3];
            *reinterpret_cast<float4*>(&G[(t << 6) + ((l + (t << 2)) & 63)]) = w;
        }
    }
    __syncthreads();
    const float sv = P[t];                                 // lane l holds sm_l
    if (isQR) {                                            // wave0 fetches its U row
        #pragma unroll
        for (int l = 0; l < N; l += 4) {
            const float4 u = *reinterpret_cast<const float4*>(
                &G[(t << 6) + ((l + (t << 2)) & 63)]);
            a[l] = u.x; a[l + 1] = u.y; a[l + 2] = u.z; a[l + 3] = u.w;
        }
    }
    #pragma unroll
    for (int l = 0; l < N; ++l) a[l] = rl(sv, l) * a[l];   // w[l] = sm[l] * U[t][l]
    const int jbase = isQR ? 0 : 32;                       // each wave: 32 output cols
    #pragma unroll 2
    for (int jj = 0; jj < 32; ++jj) {                      // X[t][j]; store [j][t] (symmetric)
        const int j = jbase + jj;
        float e0 = 0.f, e1 = 0.f, e2 = 0.f, e3 = 0.f;
        #pragma unroll
        for (int l = 0; l < N; l += 4) {
            const float4 u4 = *reinterpret_cast<const float4*>(
                &G[(j << 6) + ((l + (j << 2)) & 63)]);
            e0 = fmaf(a[l + 0], u4.x, e0);
            e1 = fmaf(a[l + 1], u4.y, e1);
            e2 = fmaf(a[l + 2], u4.z, e2);
            e3 = fmaf(a[l + 3], u4.w, e3);
        }
        out[j * N + t] = (e0 + e1) + (e2 + e3);            // coalesced
    }
}

extern "C" void kernel_launch(void* const* d_in, const int* in_sizes, int n_in,
                              void* d_out, int out_size, void* d_ws, size_t ws_size,
                              hipStream_t stream) {
    const float* in = (const float*)d_in[0];
    float* out = (float*)d_out;
    const int batch = in_sizes[0] / (N * N);
    hipLaunchKernelGGL(logm_kernel, dim3(batch), dim3(128), 0, stream, in, out);
}

// Round 5
// 1913.647 us; speedup vs baseline: 1.9144x; 1.9144x over previous
//
#include <hip/hip_runtime.h>
#include <math.h>

#define N 64
#define MAX_ITER 5

__device__ __forceinline__ float rl(float x, int lane) {
    return __uint_as_float(__builtin_amdgcn_readlane(__float_as_uint(x), lane));
}

// One 64-thread wave per 64x64 SPD matrix. Single wave, no barriers.
// Phase 1 (registers): fused Householder QR on columns a[] + Qt rows qt[]
// (deferred-coefficient trick) — verbatim from the best measured kernel.
// Archive: G row t = column t (rotation swizzle col->(col+4t)&63), diag := v0.
// col<row region of G = V, col>row = R; R-diag kept in regs (alS).
// KEY CHANGE vs best (1355 us): qt[] was live-but-COLD across the phase-2
// k-loop; LLVM's greedy RA spills cold 64-float ranges around loops by cost
// model even with 130 free VGPRs (measured: 328 MB scratch = exactly one
// array/iter; attributes (64,2)/(64,3)/waves_per_eu all failed to stop it).
// Fix: make qt DEAD there — explicit stash to Q2 (LDS) after the archive,
// full reload after the r-pass. Dead ranges can't spill. r-pass runs
// IN-PLACE on a[] (dead post-archive), removing the r[] array entirely.
// LDS = G + Q2 = 32768 B exactly -> 5 blocks/CU. Epilogue reads U rows
// straight from Q2.
__global__ __launch_bounds__(64)
__attribute__((amdgpu_waves_per_eu(1, 2)))
void logm_kernel(const float* __restrict__ gin, float* __restrict__ gout) {
    __shared__ __align__(16) float G[N * N];   // V/R archive
    __shared__ __align__(16) float Q2[N * N];  // qt stash during r-pass; U rows in epilogue
    const int t = threadIdx.x;
    const long b = blockIdx.x;
    const float* __restrict__ in = gin + b * (long)(N * N);
    float* __restrict__ out = gout + b * (long)(N * N);

    float a[N], qt[N];

    #pragma unroll
    for (int i = 0; i < N; ++i) a[i] = in[i * N + t];
    #pragma unroll
    for (int i = 0; i < N; ++i) qt[i] = (i == t) ? 1.0f : 0.0f;

    float betaS = 0.f, v0S = 0.f, alS = 0.f;  // lane k stashes beta_k / v0_k / alpha_k

    for (int iter = 0; iter < MAX_ITER; ++iter) {
        // ================= Phase 1: Householder QR, fused register passes =================
        float dotA, dotQ, wA, wQ;
        {   // prologue: deferred dot for k=0 (raw coefficient x0 at i=0), w = row 0
            float dA0 = 0.f, dA1 = 0.f, dQ0 = 0.f, dQ1 = 0.f;
            #pragma unroll
            for (int i = 0; i < N; ++i) {
                const float c = rl(a[i], 0);
                if (i & 1) { dA1 = fmaf(c, a[i], dA1); dQ1 = fmaf(c, qt[i], dQ1); }
                else       { dA0 = fmaf(c, a[i], dA0); dQ0 = fmaf(c, qt[i], dQ0); }
            }
            dotA = dA0 + dA1; dotQ = dQ0 + dQ1;
            wA = a[0]; wQ = qt[0];
        }

        #pragma unroll
        for (int kb = 0; kb < 8; ++kb) {
            const int dkEnd = (kb == 7) ? 7 : 8;          // k stops at 62
            for (int dk = 0; dk < dkEnd; ++dk) {
                const int k = 8 * kb + dk;
                const int k1 = k + 1;
                const float ss = rl(dotA, k);             // tail norm ||A[k:,k]||^2
                const float x0 = rl(wA, k);               // A[k][k]
                const float nrm = sqrtf(ss);
                const float alpha = (x0 >= 0.f) ? -nrm : nrm;
                const float v0 = x0 - alpha;
                const float vtv = fmaf(v0, v0, ss - x0 * x0);
                const float beta = (vtv > 1e-30f) ? __fdividef(2.0f, vtv) : 0.f;
                const float ca = beta * fmaf(-alpha, wA, dotA);   // deferred-coef fix
                const float cq = beta * fmaf(-alpha, wQ, dotQ);
                const float caE = (t > k) ? ca : 0.f;     // freeze columns <= k
                betaS = (t == k) ? beta  : betaS;
                v0S   = (t == k) ? v0    : v0S;
                alS   = (t == k) ? alpha : alS;

                float nA0 = 0.f, nA1 = 0.f, nQ0 = 0.f, nQ1 = 0.f, nwA = 0.f, nwQ = 0.f;
                #pragma unroll
                for (int i0 = 8 * kb; i0 < N; i0 += 8) {  // compile-time range per kb
                    #pragma unroll
                    for (int u = 0; u < 8; ++u) {
                        const int i = i0 + u;
                        float cu = rl(a[i], k);           // v_k[i] from lane k
                        if (i0 == 8 * kb) cu = (i > k) ? cu : ((i == k) ? v0 : 0.f);
                        a[i]  = fmaf(-caE, cu, a[i]);
                        qt[i] = fmaf(-cq,  cu, qt[i]);
                        float c2 = rl(a[i], k1);          // post-update col k+1 (raw)
                        if (i0 == 8 * kb) c2 = (i > k) ? c2 : 0.f;
                        if (u & 1) { nA1 = fmaf(c2, a[i], nA1); nQ1 = fmaf(c2, qt[i], nQ1); }
                        else       { nA0 = fmaf(c2, a[i], nA0); nQ0 = fmaf(c2, qt[i], nQ0); }
                        if ((i0 == 8 * kb && u > 0) || (kb < 7 && i0 == 8 * kb + 8 && u == 0)) {
                            const bool e = (i == k1);
                            nwA = e ? a[i]  : nwA;
                            nwQ = e ? qt[i] : nwQ;
                        }
                    }
                }
                dotA = nA0 + nA1; dotQ = nQ0 + nQ1; wA = nwA; wQ = nwQ;
            }
        }

        // ====== Archive columns -> G rows (swizzled); diag := v0 (V's diagonal) ======
        const float diagR = (t == N - 1) ? a[N - 1] : alS;  // R's diagonal (reg)
        #pragma unroll
        for (int j = 0; j < N; j += 4) {
            float4 w; w.x = a[j]; w.y = a[j + 1]; w.z = a[j + 2]; w.w = a[j + 3];
            *reinterpret_cast<float4*>(&G[(t << 6) + ((j + (t << 2)) & 63)]) = w;
        }
        G[(t << 6) + ((5 * t) & 63)] = v0S;               // diag of row t = v0_t

        // ====== Stash qt -> Q2 (qt becomes DEAD for the whole r-pass) ======
        #pragma unroll
        for (int j = 0; j < N; j += 4) {
            float4 w; w.x = qt[j]; w.y = qt[j + 1]; w.z = qt[j + 2]; w.w = qt[j + 3];
            *reinterpret_cast<float4*>(&Q2[(t << 6) + ((j + (t << 2)) & 63)]) = w;
        }

        // ==== r-pass init (IN PLACE on a[]): a = row t of R; dR = v_0 . a ====
        float dR;
        {
            #pragma unroll
            for (int j = 0; j < N; ++j) {                 // per-lane column read
                const float g = G[(j << 6) + ((t + (j << 2)) & 63)];
                a[j] = (j > t) ? g : ((j == t) ? diagR : 0.f);
            }
            float d0 = 0.f, d1 = 0.f;
            #pragma unroll
            for (int j = 0; j < N; j += 4) {              // row 0: identity swizzle; broadcast
                const float4 v = *reinterpret_cast<const float4*>(&G[j]);
                d0 = fmaf(v.x, a[j],     d0);
                d1 = fmaf(v.y, a[j + 1], d1);
                d0 = fmaf(v.z, a[j + 2], d0);
                d1 = fmaf(v.w, a[j + 3], d1);
            }
            dR = d0 + d1;
        }

        // ===== r-pass: a <- a * H0..H62; v_k, v_{k+1} broadcast from G rows =====
        for (int k = 0; k < N - 1; ++k) {
            const int k1 = k + 1;
            const float cc = rl(betaS, k) * dR;
            float nD0 = 0.f, nD1 = 0.f;
            #pragma unroll
            for (int j0 = 0; j0 < N; j0 += 8) {
                if (j0 + 8 > k) {                         // uniform skip of dead blocks
                    #pragma unroll
                    for (int h = 0; h < 2; ++h) {
                        const int jc = j0 + 4 * h;
                        float4 vk  = *reinterpret_cast<const float4*>(
                            &G[(k  << 6) + ((jc + (k  << 2)) & 63)]);
                        float4 vk1 = *reinterpret_cast<const float4*>(
                            &G[(k1 << 6) + ((jc + (k1 << 2)) & 63)]);
                        if (jc <= k) {                    // only the block containing k
                            vk.x  = (jc + 0 >= k)  ? vk.x  : 0.f;   // j==k keeps diag = v0
                            vk.y  = (jc + 1 >= k)  ? vk.y  : 0.f;
                            vk.z  = (jc + 2 >= k)  ? vk.z  : 0.f;
                            vk.w  = (jc + 3 >= k)  ? vk.w  : 0.f;
                            vk1.x = (jc + 0 >= k1) ? vk1.x : 0.f;
                            vk1.y = (jc + 1 >= k1) ? vk1.y : 0.f;
                            vk1.z = (jc + 2 >= k1) ? vk1.z : 0.f;
                            vk1.w = (jc + 3 >= k1) ? vk1.w : 0.f;
                        }
                        a[jc + 0] = fmaf(-cc, vk.x, a[jc + 0]); nD0 = fmaf(vk1.x, a[jc + 0], nD0);
                        a[jc + 1] = fmaf(-cc, vk.y, a[jc + 1]); nD1 = fmaf(vk1.y, a[jc + 1], nD1);
                        a[jc + 2] = fmaf(-cc, vk.z, a[jc + 2]); nD0 = fmaf(vk1.z, a[jc + 2], nD0);
                        a[jc + 3] = fmaf(-cc, vk.w, a[jc + 3]); nD1 = fmaf(vk1.w, a[jc + 3], nD1);
                    }
                }
            }
            dR = nD0 + nD1;
        }
        // a[] now = rows of A_next = columns of next A (symmetry).

        // ====== Reload qt <- Q2 (fully redefined; hot again for next P1 / epilogue) ======
        #pragma unroll
        for (int j = 0; j < N; j += 4) {
            const float4 w = *reinterpret_cast<const float4*>(
                &Q2[(t << 6) + ((j + (t << 2)) & 63)]);
            qt[j] = w.x; qt[j + 1] = w.y; qt[j + 2] = w.z; qt[j + 3] = w.w;
        }
    }

    // ======= Epilogue: sm = log(clip(diag)), w = sm .* U-row, X = w . U^T =======
    // Q2 still holds U rows (swizzled) from the last stash — read them directly.
    #pragma unroll
    for (int l = 0; l < N; ++l) {
        const float dl = rl(a[l], l);                     // A5[l][l]
        const float sml = __logf(fmaxf(dl, 1e-6f));
        a[l] = sml * qt[l];                               // w[l] = sm[l] * U[t][l]
    }
    #pragma unroll 2
    for (int j = 0; j < N; ++j) {                         // X[t][j]; store [j][t] (symmetric)
        float e0 = 0.f, e1 = 0.f, e2 = 0.f, e3 = 0.f;
        #pragma unroll
        for (int l = 0; l < N; l += 4) {
            const float4 u4 = *reinterpret_cast<const float4*>(
                &Q2[(j << 6) + ((l + (j << 2)) & 63)]);
            e0 = fmaf(a[l + 0], u4.x, e0);
            e1 = fmaf(a[l + 1], u4.y, e1);
            e2 = fmaf(a[l + 2], u4.z, e2);
            e3 = fmaf(a[l + 3], u4.w, e3);
        }
        out[j * N + t] = (e0 + e1) + (e2 + e3);           // coalesced
    }
}

extern "C" void kernel_launch(void* const* d_in, const int* in_sizes, int n_in,
                              void* d_out, int out_size, void* d_ws, size_t ws_size,
                              hipStream_t stream) {
    const float* in = (const float*)d_in[0];
    float* out = (float*)d_out;
    const int batch = in_sizes[0] / (N * N);
    hipLaunchKernelGGL(logm_kernel, dim3(batch), dim3(64), 0, stream, in, out);
}

// Round 6
// 1714.246 us; speedup vs baseline: 2.1371x; 1.1163x over previous
//
#include <hip/hip_runtime.h>
#include <math.h>

#define N 64
#define MAX_ITER 5

__device__ __forceinline__ float rl(float x, int lane) {
    return __uint_as_float(__builtin_amdgcn_readlane(__float_as_uint(x), lane));
}

// One 64-thread wave per 64x64 SPD matrix. Single wave, no barriers.
// R5 post-mortem: spill fixed (WRITE 395->132MB) but dur WORSE (1913us) —
// 32KB LDS capped residency at ~4 waves/CU; the 63-step serial Householder
// chain has nothing to hide its latency. This version:
//  (a) ONE 16KB LDS buffer GQ, time-shared: [stash qt] during phase 1,
//      [V/R archive] during the fused pass, [U rows] at the epilogue.
//      Liveness is disjoint by construction: stash at iter END -> P1 (qt
//      dead, stash live) -> reload qt -> archive overwrites (stash dead) ->
//      fused pass reads archive. 16KB -> 10 blocks/CU by LDS.
//  (b) Qt update FUSED into the r-pass k-loop (same sparsity: v_k[j]=0 for
//      j<k), sharing the vk/vk1 LDS broadcasts: qt is HOT there (no cold
//      range for the RA to spill) and phase 1 drops all qt work (~25% fewer
//      instrs + shorter serial chain).
// Pieces individually validated: A-only P1 = R4 wave-0; broadcast-Qt k-loop
// = R4 wave-1; r-path = R2/R5. All passed at absmax 0.0078125.
__global__ __launch_bounds__(64)
__attribute__((amdgpu_waves_per_eu(1, 2)))
void logm_kernel(const float* __restrict__ gin, float* __restrict__ gout) {
    __shared__ __align__(16) float GQ[N * N];  // 16384 B, time-shared (see above)
    const int t = threadIdx.x;
    const long b = blockIdx.x;
    const float* __restrict__ in = gin + b * (long)(N * N);
    float* __restrict__ out = gout + b * (long)(N * N);

    float a[N], qt[N];

    #pragma unroll
    for (int i = 0; i < N; ++i) a[i] = in[i * N + t];
    #pragma unroll
    for (int i = 0; i < N; ++i) qt[i] = (i == t) ? 1.0f : 0.0f;

    float betaS = 0.f, v0S = 0.f, alS = 0.f;  // lane k stashes beta_k / v0_k / alpha_k

    // Pre-loop stash (identity): GQ := qt rows, rotation-swizzled
    #pragma unroll
    for (int j = 0; j < N; j += 4) {
        float4 w; w.x = qt[j]; w.y = qt[j + 1]; w.z = qt[j + 2]; w.w = qt[j + 3];
        *reinterpret_cast<float4*>(&GQ[(t << 6) + ((j + (t << 2)) & 63)]) = w;
    }

    for (int iter = 0; iter < MAX_ITER; ++iter) {
        // ========== Phase 1: Householder QR on a[] only (GQ holds stashed qt) ==========
        float dotA, wA;
        {   // prologue: deferred dot for k=0 (raw coefficient x0 at i=0)
            float dA0 = 0.f, dA1 = 0.f;
            #pragma unroll
            for (int i = 0; i < N; ++i) {
                const float c = rl(a[i], 0);
                if (i & 1) dA1 = fmaf(c, a[i], dA1);
                else       dA0 = fmaf(c, a[i], dA0);
            }
            dotA = dA0 + dA1; wA = a[0];
        }
        #pragma unroll
        for (int kb = 0; kb < 8; ++kb) {
            const int dkEnd = (kb == 7) ? 7 : 8;          // k stops at 62
            for (int dk = 0; dk < dkEnd; ++dk) {
                const int k = 8 * kb + dk;
                const int k1 = k + 1;
                const float ss = rl(dotA, k);             // tail norm ||A[k:,k]||^2
                const float x0 = rl(wA, k);               // A[k][k]
                const float nrm = sqrtf(ss);
                const float alpha = (x0 >= 0.f) ? -nrm : nrm;
                const float v0 = x0 - alpha;
                const float vtv = fmaf(v0, v0, ss - x0 * x0);
                const float beta = (vtv > 1e-30f) ? __fdividef(2.0f, vtv) : 0.f;
                const float ca = beta * fmaf(-alpha, wA, dotA);  // deferred-coef fix
                const float caE = (t > k) ? ca : 0.f;     // freeze columns <= k
                betaS = (t == k) ? beta  : betaS;
                v0S   = (t == k) ? v0    : v0S;
                alS   = (t == k) ? alpha : alS;

                float nA0 = 0.f, nA1 = 0.f, nwA = 0.f;
                #pragma unroll
                for (int i0 = 8 * kb; i0 < N; i0 += 8) {  // compile-time range per kb
                    #pragma unroll
                    for (int u = 0; u < 8; ++u) {
                        const int i = i0 + u;
                        float cu = rl(a[i], k);           // v_k[i] from lane k
                        if (i0 == 8 * kb) cu = (i > k) ? cu : ((i == k) ? v0 : 0.f);
                        a[i] = fmaf(-caE, cu, a[i]);
                        float c2 = rl(a[i], k1);          // post-update col k+1 (raw)
                        if (i0 == 8 * kb) c2 = (i > k) ? c2 : 0.f;
                        if (u & 1) nA1 = fmaf(c2, a[i], nA1);
                        else       nA0 = fmaf(c2, a[i], nA0);
                        if ((i0 == 8 * kb && u > 0) || (kb < 7 && i0 == 8 * kb + 8 && u == 0)) {
                            nwA = (i == k1) ? a[i] : nwA;
                        }
                    }
                }
                dotA = nA0 + nA1; wA = nwA;
            }
        }
        const float diagR = (t == N - 1) ? a[N - 1] : alS;  // R's diagonal (reg)

        // ====== Reload qt <- GQ (must precede the archive overwrite) ======
        #pragma unroll
        for (int j = 0; j < N; j += 4) {
            const float4 w = *reinterpret_cast<const float4*>(
                &GQ[(t << 6) + ((j + (t << 2)) & 63)]);
            qt[j] = w.x; qt[j + 1] = w.y; qt[j + 2] = w.z; qt[j + 3] = w.w;
        }

        // ====== Archive columns -> GQ rows (swizzled); diag := v0 (V's diagonal) ======
        #pragma unroll
        for (int j = 0; j < N; j += 4) {
            float4 w; w.x = a[j]; w.y = a[j + 1]; w.z = a[j + 2]; w.w = a[j + 3];
            *reinterpret_cast<float4*>(&GQ[(t << 6) + ((j + (t << 2)) & 63)]) = w;
        }
        GQ[(t << 6) + ((5 * t) & 63)] = v0S;              // diag of row t = v0_t

        // ==== Fused-pass init: a := row t of R (in place); dR = v0.a, dQ = v0.qt ====
        float dR, dQ;
        {
            #pragma unroll
            for (int j = 0; j < N; ++j) {                 // per-lane column read
                const float g = GQ[(j << 6) + ((t + (j << 2)) & 63)];
                a[j] = (j > t) ? g : ((j == t) ? diagR : 0.f);
            }
            float d0 = 0.f, d1 = 0.f, e0 = 0.f, e1 = 0.f;
            #pragma unroll
            for (int j = 0; j < N; j += 4) {              // row 0: identity swizzle = exact v_0
                const float4 v = *reinterpret_cast<const float4*>(&GQ[j]);
                d0 = fmaf(v.x, a[j],      d0);
                d1 = fmaf(v.y, a[j + 1],  d1);
                d0 = fmaf(v.z, a[j + 2],  d0);
                d1 = fmaf(v.w, a[j + 3],  d1);
                e0 = fmaf(v.x, qt[j],     e0);
                e1 = fmaf(v.y, qt[j + 1], e1);
                e0 = fmaf(v.z, qt[j + 2], e0);
                e1 = fmaf(v.w, qt[j + 3], e1);
            }
            dR = d0 + d1; dQ = e0 + e1;
        }

        // ===== Fused pass: a <- a*H0..H62 (rows of A_next) AND qt <- qt*H0..H62 =====
        for (int k = 0; k < N - 1; ++k) {
            const int k1 = k + 1;
            const float bk = rl(betaS, k);
            const float ccR = bk * dR;
            const float ccQ = bk * dQ;
            float nR0 = 0.f, nR1 = 0.f, nQ0 = 0.f, nQ1 = 0.f;
            #pragma unroll
            for (int j0 = 0; j0 < N; j0 += 8) {
                if (j0 + 8 > k) {                         // uniform skip of dead blocks
                    #pragma unroll
                    for (int h = 0; h < 2; ++h) {
                        const int jc = j0 + 4 * h;
                        float4 vk  = *reinterpret_cast<const float4*>(
                            &GQ[(k  << 6) + ((jc + (k  << 2)) & 63)]);
                        float4 vk1 = *reinterpret_cast<const float4*>(
                            &GQ[(k1 << 6) + ((jc + (k1 << 2)) & 63)]);
                        if (jc <= k) {                    // only the block containing k
                            vk.x  = (jc + 0 >= k)  ? vk.x  : 0.f;   // j==k keeps diag = v0
                            vk.y  = (jc + 1 >= k)  ? vk.y  : 0.f;
                            vk.z  = (jc + 2 >= k)  ? vk.z  : 0.f;
                            vk.w  = (jc + 3 >= k)  ? vk.w  : 0.f;
                            vk1.x = (jc + 0 >= k1) ? vk1.x : 0.f;
                            vk1.y = (jc + 1 >= k1) ? vk1.y : 0.f;
                            vk1.z = (jc + 2 >= k1) ? vk1.z : 0.f;
                            vk1.w = (jc + 3 >= k1) ? vk1.w : 0.f;
                        }
                        a[jc + 0]  = fmaf(-ccR, vk.x, a[jc + 0]);  nR0 = fmaf(vk1.x, a[jc + 0],  nR0);
                        qt[jc + 0] = fmaf(-ccQ, vk.x, qt[jc + 0]); nQ0 = fmaf(vk1.x, qt[jc + 0], nQ0);
                        a[jc + 1]  = fmaf(-ccR, vk.y, a[jc + 1]);  nR1 = fmaf(vk1.y, a[jc + 1],  nR1);
                        qt[jc + 1] = fmaf(-ccQ, vk.y, qt[jc + 1]); nQ1 = fmaf(vk1.y, qt[jc + 1], nQ1);
                        a[jc + 2]  = fmaf(-ccR, vk.z, a[jc + 2]);  nR0 = fmaf(vk1.z, a[jc + 2],  nR0);
                        qt[jc + 2] = fmaf(-ccQ, vk.z, qt[jc + 2]); nQ0 = fmaf(vk1.z, qt[jc + 2], nQ0);
                        a[jc + 3]  = fmaf(-ccR, vk.w, a[jc + 3]);  nR1 = fmaf(vk1.w, a[jc + 3],  nR1);
                        qt[jc + 3] = fmaf(-ccQ, vk.w, qt[jc + 3]); nQ1 = fmaf(vk1.w, qt[jc + 3], nQ1);
                    }
                }
            }
            dR = nR0 + nR1; dQ = nQ0 + nQ1;
        }
        // a[] = rows of A_next = columns of next A (symmetry). qt[] = updated Qt rows.

        // ====== Stash qt -> GQ (V/R dead now; after last iter this is the U archive) ======
        #pragma unroll
        for (int j = 0; j < N; j += 4) {
            float4 w; w.x = qt[j]; w.y = qt[j + 1]; w.z = qt[j + 2]; w.w = qt[j + 3];
            *reinterpret_cast<float4*>(&GQ[(t << 6) + ((j + (t << 2)) & 63)]) = w;
        }
    }

    // ======= Epilogue: sm = log(clip(diag)), w = sm .* U-row, X = w . U^T =======
    // GQ holds U rows (swizzled) from the final stash; qt still hot in regs.
    #pragma unroll
    for (int l = 0; l < N; ++l) {
        const float dl = rl(a[l], l);                     // A5[l][l]
        const float sml = __logf(fmaxf(dl, 1e-6f));
        a[l] = sml * qt[l];                               // w[l] = sm[l] * U[t][l]
    }
    #pragma unroll 2
    for (int j = 0; j < N; ++j) {                         // X[t][j]; store [j][t] (symmetric)
        float e0 = 0.f, e1 = 0.f, e2 = 0.f, e3 = 0.f;
        #pragma unroll
        for (int l = 0; l < N; l += 4) {
            const float4 u4 = *reinterpret_cast<const float4*>(
                &GQ[(j << 6) + ((l + (j << 2)) & 63)]);
            e0 = fmaf(a[l + 0], u4.x, e0);
            e1 = fmaf(a[l + 1], u4.y, e1);
            e2 = fmaf(a[l + 2], u4.z, e2);
            e3 = fmaf(a[l + 3], u4.w, e3);
        }
        out[j * N + t] = (e0 + e1) + (e2 + e3);           // coalesced
    }
}

extern "C" void kernel_launch(void* const* d_in, const int* in_sizes, int n_in,
                              void* d_out, int out_size, void* d_ws, size_t ws_size,
                              hipStream_t stream) {
    const float* in = (const float*)d_in[0];
    float* out = (float*)d_out;
    const int batch = in_sizes[0] / (N * N);
    hipLaunchKernelGGL(logm_kernel, dim3(batch), dim3(64), 0, stream, in, out);
}

// Round 7
// 1166.320 us; speedup vs baseline: 3.1410x; 1.4698x over previous
//
#include <hip/hip_runtime.h>
#include <math.h>

#define N 64
#define GS 68   // LDS row stride (floats); 272 B rows, b128-aligned, 8-way-max banking
#define MAX_ITER 5

__device__ __forceinline__ float rl(float x, int lane) {
    return __uint_as_float(__builtin_amdgcn_readlane(__float_as_uint(x), lane));
}

// One 64-thread wave per 64x64 SPD matrix — R2 structure (best measured, 1355us)
// + instruction diet. Cross-round model: wall ~ 1/(resident waves); R2's RA
// scratch-spill of cold qt[] is the CHEAPEST parking (HBM traffic hidden by 10
// waves/CU) vs LDS stash (R5: 5 blocks/CU, 1913us) or fused-in-regs (R6: 164
// VGPR -> 2-waves/SIMD bucket, 1714us). So: keep qt cold/spilled, keep VGPR
// <=128, and cut phase-2 instruction fat:
//  (a) GS=68 plain layout (no rotation swizzle): k-loop broadcast reads are
//      base + compile-time offsets -> ds_read_b128 offset:imm, ~2 VALU/k-step
//      vs ~60 for swizzled address math. Archive stores / R-init column reads
//      are 8-way / conflict-free at stride 68 (cheap).
//  (b) After the R-row init reads the R region, each lane rewrites its row as
//      the EXACT v_t (0 below diag, v0 at diag, tail above): all 315 k-steps
//      lose their cndmask boundary masking and the jc<=k branch split.
// Replaced expressions are arithmetically identical (fmaf(-cc,0,r) == before),
// so the A/R/Q trajectory is bit-exact vs the 1355us kernel.
__global__ __launch_bounds__(64)
__attribute__((amdgpu_waves_per_eu(1, 2)))
void logm_kernel(const float* __restrict__ gin, float* __restrict__ gout) {
    __shared__ __align__(16) float G[N * GS];  // 17408 B -> 9 blocks/CU
    const int t = threadIdx.x;
    const long b = blockIdx.x;
    const float* __restrict__ in = gin + b * (long)(N * N);
    float* __restrict__ out = gout + b * (long)(N * N);

    float a[N], r[N], qt[N];

    #pragma unroll
    for (int i = 0; i < N; ++i) a[i] = in[i * N + t];
    #pragma unroll
    for (int i = 0; i < N; ++i) qt[i] = (i == t) ? 1.0f : 0.0f;

    float betaS = 0.f, v0S = 0.f, alS = 0.f;  // lane k stashes beta_k / v0_k / alpha_k

    for (int iter = 0; iter < MAX_ITER; ++iter) {
        // ================= Phase 1: Householder QR, fused register passes =================
        float dotA, dotQ, wA, wQ;
        {   // prologue: deferred dot for k=0 (raw coefficient x0 at i=0), w = row 0
            float dA0 = 0.f, dA1 = 0.f, dQ0 = 0.f, dQ1 = 0.f;
            #pragma unroll
            for (int i = 0; i < N; ++i) {
                const float c = rl(a[i], 0);
                if (i & 1) { dA1 = fmaf(c, a[i], dA1); dQ1 = fmaf(c, qt[i], dQ1); }
                else       { dA0 = fmaf(c, a[i], dA0); dQ0 = fmaf(c, qt[i], dQ0); }
            }
            dotA = dA0 + dA1; dotQ = dQ0 + dQ1;
            wA = a[0]; wQ = qt[0];
        }

        #pragma unroll
        for (int kb = 0; kb < 8; ++kb) {
            const int dkEnd = (kb == 7) ? 7 : 8;          // k stops at 62
            for (int dk = 0; dk < dkEnd; ++dk) {
                const int k = 8 * kb + dk;
                const int k1 = k + 1;
                const float ss = rl(dotA, k);             // tail norm ||A[k:,k]||^2
                const float x0 = rl(wA, k);               // A[k][k]
                const float nrm = sqrtf(ss);
                const float alpha = (x0 >= 0.f) ? -nrm : nrm;
                const float v0 = x0 - alpha;
                const float vtv = fmaf(v0, v0, ss - x0 * x0);
                const float beta = (vtv > 1e-30f) ? __fdividef(2.0f, vtv) : 0.f;
                const float ca = beta * fmaf(-alpha, wA, dotA);   // deferred-coef fix
                const float cq = beta * fmaf(-alpha, wQ, dotQ);
                const float caE = (t > k) ? ca : 0.f;     // freeze columns <= k
                betaS = (t == k) ? beta  : betaS;
                v0S   = (t == k) ? v0    : v0S;
                alS   = (t == k) ? alpha : alS;

                float nA0 = 0.f, nA1 = 0.f, nQ0 = 0.f, nQ1 = 0.f, nwA = 0.f, nwQ = 0.f;
                #pragma unroll
                for (int i0 = 8 * kb; i0 < N; i0 += 8) {  // compile-time range per kb
                    #pragma unroll
                    for (int u = 0; u < 8; ++u) {
                        const int i = i0 + u;
                        float cu = rl(a[i], k);           // v_k[i] from lane k
                        if (i0 == 8 * kb) cu = (i > k) ? cu : ((i == k) ? v0 : 0.f);
                        a[i]  = fmaf(-caE, cu, a[i]);
                        qt[i] = fmaf(-cq,  cu, qt[i]);
                        float c2 = rl(a[i], k1);          // post-update col k+1 (raw)
                        if (i0 == 8 * kb) c2 = (i > k) ? c2 : 0.f;
                        if (u & 1) { nA1 = fmaf(c2, a[i], nA1); nQ1 = fmaf(c2, qt[i], nQ1); }
                        else       { nA0 = fmaf(c2, a[i], nA0); nQ0 = fmaf(c2, qt[i], nQ0); }
                        if ((i0 == 8 * kb && u > 0) || (kb < 7 && i0 == 8 * kb + 8 && u == 0)) {
                            const bool e = (i == k1);
                            nwA = e ? a[i]  : nwA;
                            nwQ = e ? qt[i] : nwQ;
                        }
                    }
                }
                dotA = nA0 + nA1; dotQ = nQ0 + nQ1; wA = nwA; wQ = nwQ;
            }
        }

        // ====== Archive columns -> G rows (plain, full — R region included) ======
        const float diagR = (t == N - 1) ? a[N - 1] : alS;  // R's diagonal (regs)
        #pragma unroll
        for (int j = 0; j < N; j += 4) {
            float4 w; w.x = a[j]; w.y = a[j + 1]; w.z = a[j + 2]; w.w = a[j + 3];
            *reinterpret_cast<float4*>(&G[t * GS + j]) = w;
        }

        // ==== Init r = row t of R via column read (conflict-free at stride 68) ====
        #pragma unroll
        for (int j = 0; j < N; ++j) {
            const float g = G[j * GS + t];
            r[j] = (j > t) ? g : ((j == t) ? diagR : 0.f);
        }

        // ==== Clean: row t := exact v_t (R region dead now) — kills k-loop masks ====
        #pragma unroll
        for (int j = 0; j < N; j += 4) {
            float4 w;
            w.x = (j + 0 > t) ? a[j + 0] : 0.f;
            w.y = (j + 1 > t) ? a[j + 1] : 0.f;
            w.z = (j + 2 > t) ? a[j + 2] : 0.f;
            w.w = (j + 3 > t) ? a[j + 3] : 0.f;
            *reinterpret_cast<float4*>(&G[t * GS + j]) = w;
        }
        G[t * GS + t] = v0S;                              // diag of row t = v0_t

        // ==== dR prologue: row 0 (= exact v_0) dot r ====
        float dR;
        {
            float d0 = 0.f, d1 = 0.f;
            #pragma unroll
            for (int j = 0; j < N; j += 4) {
                const float4 v = *reinterpret_cast<const float4*>(&G[j]);
                d0 = fmaf(v.x, r[j],     d0);
                d1 = fmaf(v.y, r[j + 1], d1);
                d0 = fmaf(v.z, r[j + 2], d0);
                d1 = fmaf(v.w, r[j + 3], d1);
            }
            dR = d0 + d1;
        }

        // ===== k-loop: mask-free; rows k,k+1 via base pointer + offset immediates =====
        for (int k = 0; k < N - 1; ++k) {
            const float cc = rl(betaS, k) * dR;
            const float* __restrict__ rowk = &G[k * GS];  // one addr per k-step
            float nD0 = 0.f, nD1 = 0.f;
            #pragma unroll
            for (int j0 = 0; j0 < N; j0 += 8) {
                if (j0 + 8 > k) {                         // uniform skip of dead blocks
                    #pragma unroll
                    for (int h = 0; h < 2; ++h) {
                        const int jc = j0 + 4 * h;
                        const float4 vk  = *reinterpret_cast<const float4*>(rowk + jc);
                        const float4 vk1 = *reinterpret_cast<const float4*>(rowk + GS + jc);
                        r[jc + 0] = fmaf(-cc, vk.x, r[jc + 0]); nD0 = fmaf(vk1.x, r[jc + 0], nD0);
                        r[jc + 1] = fmaf(-cc, vk.y, r[jc + 1]); nD1 = fmaf(vk1.y, r[jc + 1], nD1);
                        r[jc + 2] = fmaf(-cc, vk.z, r[jc + 2]); nD0 = fmaf(vk1.z, r[jc + 2], nD0);
                        r[jc + 3] = fmaf(-cc, vk.w, r[jc + 3]); nD1 = fmaf(vk1.w, r[jc + 3], nD1);
                    }
                }
            }
            dR = nD0 + nD1;
        }
        #pragma unroll
        for (int j = 0; j < N; ++j) a[j] = r[j];          // symmetric: rows -> next cols
    }

    // ======= Epilogue: sm = log(clip(diag)), w = sm .* U-row, X = w . U^T =======
    #pragma unroll
    for (int l = 0; l < N; ++l) {
        const float dl = rl(a[l], l);                     // A5[l][l]
        const float sml = __logf(fmaxf(dl, 1e-6f));
        a[l] = sml * qt[l];                               // w[l] = sm[l] * U[t][l]
    }
    #pragma unroll
    for (int l = 0; l < N; l += 4) {                      // U rows -> G
        float4 w; w.x = qt[l]; w.y = qt[l + 1]; w.z = qt[l + 2]; w.w = qt[l + 3];
        *reinterpret_cast<float4*>(&G[t * GS + l]) = w;
    }
    #pragma unroll 2
    for (int j = 0; j < N; ++j) {                         // X[t][j]; store [j][t] (symmetric)
        float e0 = 0.f, e1 = 0.f, e2 = 0.f, e3 = 0.f;
        #pragma unroll
        for (int l = 0; l < N; l += 4) {
            const float4 u4 = *reinterpret_cast<const float4*>(&G[j * GS + l]);
            e0 = fmaf(a[l + 0], u4.x, e0);
            e1 = fmaf(a[l + 1], u4.y, e1);
            e2 = fmaf(a[l + 2], u4.z, e2);
            e3 = fmaf(a[l + 3], u4.w, e3);
        }
        out[j * N + t] = (e0 + e1) + (e2 + e3);           // coalesced
    }
}

extern "C" void kernel_launch(void* const* d_in, const int* in_sizes, int n_in,
                              void* d_out, int out_size, void* d_ws, size_t ws_size,
                              hipStream_t stream) {
    const float* in = (const float*)d_in[0];
    float* out = (float*)d_out;
    const int batch = in_sizes[0] / (N * N);
    hipLaunchKernelGGL(logm_kernel, dim3(batch), dim3(64), 0, stream, in, out);
}